// Round 8
// baseline (209.017 us; speedup 1.0000x reference)
//
#include <hip/hip_runtime.h>
#include <hip/hip_bf16.h>

#define Bsz 4
#define Ssz 2048
#define Dsz 512
#define Hsz 8
#define DKsz 64

typedef __bf16 bf16x8 __attribute__((ext_vector_type(8)));
typedef __bf16 bf16x4 __attribute__((ext_vector_type(4)));
typedef float f32x4 __attribute__((ext_vector_type(4)));

// chunk-swizzled element offset: 16B chunk c of a 64-elem (128B) row, XOR row&7
#define SWE(c, row) ((((c) ^ ((row) & 7)) * 8))

// direct global->LDS 16B/lane copy (lane l writes lds_base + l*16)
#define GLL16(g, l) __builtin_amdgcn_global_load_lds(                      \
    (const __attribute__((address_space(1))) void*)(g),                    \
    (__attribute__((address_space(3))) void*)(l), 16, 0, 0)

// ---------------------------------------------------------------------------
// cvt: x (4.19M fp32) + Wq|Wk|Wv (3 x 262144 fp32) -> bf16 in ws.
__global__ __launch_bounds__(256) void cvt_kernel(
    const float* __restrict__ x, const float* __restrict__ Wq,
    const float* __restrict__ Wk, const float* __restrict__ Wv,
    __bf16* __restrict__ xb, __bf16* __restrict__ Wb)
{
    const int i = blockIdx.x * 256 + threadIdx.x;   // float4 index
    const int XN4 = (Bsz * Ssz * Dsz) / 4;          // 1,048,576
    const float* src;
    __bf16* dst;
    int off;
    if (i < XN4) {
        src = x; dst = xb; off = i;
    } else {
        int j = i - XN4;                             // 0 .. 196607
        int w = j >> 16;                             // 0,1,2
        off = j & 65535;
        src = (w == 0) ? Wq : (w == 1) ? Wk : Wv;
        dst = Wb + (size_t)w * (Dsz * Dsz);
    }
    float4 v = ((const float4*)src)[off];
    __bf16 o[4] = {(__bf16)v.x, (__bf16)v.y, (__bf16)v.z, (__bf16)v.w};
    *(uint2*)(dst + (size_t)off * 4) = *(uint2*)o;
}

// ---------------------------------------------------------------------------
// Fused qkv projection, L2-LOCALITY SWIZZLED grid (1-D, 768 blocks).
// Staging via global_load_lds width=16: LDS dest LINEAR (lane l -> base+16l,
// 8 rows/wave), global source chunk PRE-SWIZZLED with the read-side XOR
// involution (chunk ^= row&7) -> rule #21 satisfied, coalescing preserved.
// 128x128 tile, 2-barrier K-loop, which<2 (Q/K): C = W-tile x x-tile;
// which==2 (V): C = x-tile x W-tile -> V^T.   [verified R3-R7: passed]
__global__ __launch_bounds__(256, 3) void qkv_kernel(
    const __bf16* __restrict__ xb, const __bf16* __restrict__ Wb,
    __bf16* __restrict__ Qo, __bf16* __restrict__ Ko, __bf16* __restrict__ Vo)
{
    __shared__ __bf16 xs[128][64];
    __shared__ __bf16 wsh[128][64];

    const int tid  = threadIdx.x;
    const int lane = tid & 63;
    const int wave = tid >> 6;
    const int quad = lane >> 4;
    const int l16  = lane & 15;
    const int wm   = (wave & 1) * 64;
    const int wn   = (wave >> 1) * 64;

    const int lin = blockIdx.x;
    const int xcd = lin & 7;
    const int idx = lin >> 3;             // 0..95
    const int tnw = idx % 12;             // fast per XCD: sweeps (tn, which)
    const int tmh = idx / 12;             // slow: x-tile group
    const int tm  = (tmh * 8 + xcd) * 128;
    const int tn  = (tnw & 3) * 128;
    const int which = tnw >> 2;           // 0=Q 1=K 2=V
    const bool VM = (which == 2);
    const __bf16* W = Wb + (size_t)which * (Dsz * Dsz);

    // direct-to-LDS staging: wave covers rows [wave*8, wave*8+8) per issue,
    // lane l -> row wave*8+(l>>3), linear chunk l&7; source chunk pre-XORed.
    const int rl  = lane >> 3;            // 0..7
    const int gch = (lane & 7) ^ rl;      // pre-swizzled 16B chunk
    const __bf16* xsrc = xb + (size_t)(tm + wave * 8 + rl) * Dsz + gch * 8;
    const __bf16* wsrc = W  + (size_t)(tn + wave * 8 + rl) * Dsz + gch * 8;

    f32x4 acc[4][4];
    #pragma unroll
    for (int i = 0; i < 4; ++i)
        #pragma unroll
        for (int j = 0; j < 4; ++j) acc[i][j] = (f32x4){0.f, 0.f, 0.f, 0.f};

    const __bf16 (*Ash)[64] = VM ? xs : wsh;
    const __bf16 (*Bsh)[64] = VM ? wsh : xs;

    for (int k0 = 0; k0 < Dsz; k0 += 64) {
        __syncthreads();                  // previous tile fully consumed
        #pragma unroll
        for (int i = 0; i < 4; ++i) {
            GLL16(xsrc + (size_t)(32 * i) * Dsz + k0, &xs[wave * 8 + 32 * i][0]);
            GLL16(wsrc + (size_t)(32 * i) * Dsz + k0, &wsh[wave * 8 + 32 * i][0]);
        }
        asm volatile("s_waitcnt vmcnt(0)" ::: "memory");
        __syncthreads();

        #pragma unroll
        for (int kk = 0; kk < 2; ++kk) {
            bf16x8 fa[4], fb[4];
            #pragma unroll
            for (int mi = 0; mi < 4; ++mi) {
                const int row = wm + mi * 16 + l16;
                fa[mi] = *(const bf16x8*)&Ash[row][SWE(kk * 4 + quad, row)];
            }
            #pragma unroll
            for (int ni = 0; ni < 4; ++ni) {
                const int row = wn + ni * 16 + l16;
                fb[ni] = *(const bf16x8*)&Bsh[row][SWE(kk * 4 + quad, row)];
            }
            #pragma unroll
            for (int mi = 0; mi < 4; ++mi)
                #pragma unroll
                for (int ni = 0; ni < 4; ++ni)
                    acc[mi][ni] = __builtin_amdgcn_mfma_f32_16x16x32_bf16(
                        fa[mi], fb[ni], acc[mi][ni], 0, 0, 0);
        }
    }

    if (!VM) {
        const float scale = (which == 0) ? 0.125f * 1.44269504088896340736f : 1.0f;
        __bf16* dst = (which == 0) ? Qo : Ko;
        // rows = e (W-dim), in-lane regs r span 4 consecutive e -> 4 consecutive d
        #pragma unroll
        for (int mi = 0; mi < 4; ++mi) {
            const int e0 = tn + wm + mi * 16 + quad * 4;
            const int h = e0 >> 6, d0 = e0 & 63;
            #pragma unroll
            for (int ni = 0; ni < 4; ++ni) {
                const int sf = tm + wn + ni * 16 + l16;
                const int b = sf >> 11, s = sf & (Ssz - 1);
                bf16x4 p;
                #pragma unroll
                for (int r = 0; r < 4; ++r) p[r] = (__bf16)(acc[mi][ni][r] * scale);
                *(bf16x4*)&dst[((((size_t)(b * Hsz + h) * Ssz + s)) << 6) + d0] = p;
            }
        }
    } else {
        // rows = s, in-lane regs r span 4 consecutive s -> V^T packed stores
        #pragma unroll
        for (int mi = 0; mi < 4; ++mi) {
            const int sf0 = tm + wm + mi * 16 + quad * 4;
            const int b = sf0 >> 11, s0 = sf0 & (Ssz - 1);
            #pragma unroll
            for (int ni = 0; ni < 4; ++ni) {
                const int e = tn + wn + ni * 16 + l16;
                const int h = e >> 6, d = e & 63;
                bf16x4 p;
                #pragma unroll
                for (int r = 0; r < 4; ++r) p[r] = (__bf16)acc[mi][ni][r];
                *(bf16x4*)&Vo[(((size_t)(b * Hsz + h) * DKsz + d) << 11) + s0] = p;
            }
        }
    }
}

// ---------------------------------------------------------------------------
// Flash attention, ZERO-BARRIER / NO K-V STAGING (catalog lesson #7: staging
// L2-resident data is pure overhead — m169 dropped V-staging for +26%).
// Evidence: R7 halved staging volume -> no gain (staging volume not binding);
// R4/R5 barrier moves neutral; the cost is the barrier-coupled LDS chain
// itself. K/V per (b,h) = 512 KB; all 16 q-blocks of a bh share one XCD
// (lin id = bh+32*qt, mod 8 = bh&7) -> per-XCD K/V = 4 bh x 512 KB = 2 MB
// < 4 MB L2. So: read K/V fragments DIRECTLY global->reg (16B/lane,
// coalesced). No s_barrier anywhere; waves fully independent; register
// double-buffer kfA/kfB (static names, rule #20) prefetches K(T+1) during
// softmax/PV(T); vf(T) issues before QK(T) -> ~400 cyc cover vs ~200 cyc
// L2 latency, enforced by compiler vmcnt on pure register dataflow.
// LDS = ps only (per-wave P^T redistribution, 16 KB/block).
// S computed transposed (A=K,B=Q) -> P^T packs to b64 LDS writes; PV swapped
// (A=V^T, B=P^T) -> O^T regs -> f32x4 stores; row-sums via ones-MFMA.
__global__ __launch_bounds__(256, 2) void attn_kernel(
    const __bf16* __restrict__ Q, const __bf16* __restrict__ K,
    const __bf16* __restrict__ VT, float* __restrict__ out)
{
    __shared__ __bf16 ps[4][2][16][64];  // [wave][qs] P^T buffer, swizzled

    const int tid  = threadIdx.x;
    const int lane = tid & 63;
    const int wave = tid >> 6;
    const int quad = lane >> 4;
    const int l16  = lane & 15;

    const int bh = blockIdx.x;           // all q-blocks of a bh share an XCD L2
    const int qt = blockIdx.y;           // 128-row q tile
    const int b  = bh >> 3;
    const int h  = bh & 7;

    const __bf16* Qb = Q  + (size_t)bh * Ssz * DKsz;
    const __bf16* Kb = K  + (size_t)bh * Ssz * DKsz;
    const __bf16* Vb = VT + (size_t)bh * DKsz * Ssz;

    // Q fragments: lane l16 = q-local row, quad*8 = dk chunk
    bf16x8 qf[2][2];
    #pragma unroll
    for (int qs = 0; qs < 2; ++qs) {
        const __bf16* qrow = Qb + (size_t)(qt * 128 + wave * 32 + qs * 16 + l16) * DKsz;
        qf[qs][0] = *(const bf16x8*)(qrow + quad * 8);
        qf[qs][1] = *(const bf16x8*)(qrow + 32 + quad * 8);
    }

    bf16x8 ones;
    #pragma unroll
    for (int i = 0; i < 8; ++i) ones[i] = (__bf16)1.0f;

    f32x4 oacc[2][4];
    #pragma unroll
    for (int qs = 0; qs < 2; ++qs)
        #pragma unroll
        for (int i = 0; i < 4; ++i) oacc[qs][i] = (f32x4){0.f, 0.f, 0.f, 0.f};
    f32x4 lacc[2] = {(f32x4){0.f, 0.f, 0.f, 0.f}, (f32x4){0.f, 0.f, 0.f, 0.f}};

    // K fragment rows (s-local) and V^T fragment rows (d) use the same
    // lane geometry: row = ns*16 + l16, 16B chunk = (kk*4+quad)*8.
#define LOAD_KF(DST, KB)                                                       \
    _Pragma("unroll")                                                          \
    for (int kk = 0; kk < 2; ++kk)                                             \
        _Pragma("unroll")                                                      \
        for (int ns = 0; ns < 4; ++ns)                                         \
            DST[kk][ns] = *(const bf16x8*)(Kb                                  \
                + (size_t)((KB) + ns * 16 + l16) * DKsz + (kk * 4 + quad) * 8);

#define LOAD_VF(DST, KB)                                                       \
    _Pragma("unroll")                                                          \
    for (int kk = 0; kk < 2; ++kk)                                             \
        _Pragma("unroll")                                                      \
        for (int ns = 0; ns < 4; ++ns)                                         \
            DST[kk][ns] = *(const bf16x8*)(Vb                                  \
                + (size_t)(ns * 16 + l16) * Ssz + (KB) + (kk * 4 + quad) * 8);

    // compute one 64-KV tile with K-frags KF and V-frags VF; PREFETCH issues
    // the next tile's K loads between QK (last consumer of KF slot pairing)
    // and the softmax/PV stretch, so they land with ~500 cyc of cover.
#define ATTN_TILE(KF, VF, PREFETCH)                                            \
    do {                                                                       \
        __builtin_amdgcn_s_setprio(1);                                         \
        f32x4 st[2][4];                                                        \
        _Pragma("unroll")                                                      \
        for (int qs = 0; qs < 2; ++qs)                                         \
            _Pragma("unroll")                                                  \
            for (int ns = 0; ns < 4; ++ns) {                                   \
                f32x4 t = (f32x4){0.f, 0.f, 0.f, 0.f};                         \
                t = __builtin_amdgcn_mfma_f32_16x16x32_bf16(                   \
                        KF[0][ns], qf[qs][0], t, 0, 0, 0);                     \
                t = __builtin_amdgcn_mfma_f32_16x16x32_bf16(                   \
                        KF[1][ns], qf[qs][1], t, 0, 0, 0);                     \
                st[qs][ns] = t;                                                \
            }                                                                  \
        __builtin_amdgcn_s_setprio(0);                                         \
        PREFETCH;                                                              \
        _Pragma("unroll")                                                      \
        for (int qs = 0; qs < 2; ++qs)                                         \
            _Pragma("unroll")                                                  \
            for (int ns = 0; ns < 4; ++ns) {                                   \
                bf16x4 pp;                                                     \
                _Pragma("unroll")                                              \
                for (int r = 0; r < 4; ++r)                                    \
                    pp[r] = (__bf16)__builtin_amdgcn_exp2f(st[qs][ns][r]);     \
                const int c = ns * 2 + (quad >> 1);                            \
                *(bf16x4*)&ps[wave][qs][l16]                                   \
                    [((c ^ (l16 & 7)) << 3) + ((quad & 1) << 2)] = pp;         \
            }                                                                  \
        bf16x8 af[2][2];                                                       \
        af[0][0] = *(const bf16x8*)&ps[wave][0][l16][SWE(quad, l16)];          \
        af[0][1] = *(const bf16x8*)&ps[wave][0][l16][SWE(4 + quad, l16)];      \
        af[1][0] = *(const bf16x8*)&ps[wave][1][l16][SWE(quad, l16)];          \
        af[1][1] = *(const bf16x8*)&ps[wave][1][l16][SWE(4 + quad, l16)];      \
        __builtin_amdgcn_s_setprio(1);                                         \
        _Pragma("unroll")                                                      \
        for (int qs = 0; qs < 2; ++qs) {                                       \
            _Pragma("unroll")                                                  \
            for (int ns = 0; ns < 4; ++ns) {                                   \
                oacc[qs][ns] = __builtin_amdgcn_mfma_f32_16x16x32_bf16(        \
                    VF[0][ns], af[qs][0], oacc[qs][ns], 0, 0, 0);              \
                oacc[qs][ns] = __builtin_amdgcn_mfma_f32_16x16x32_bf16(        \
                    VF[1][ns], af[qs][1], oacc[qs][ns], 0, 0, 0);              \
            }                                                                  \
            lacc[qs] = __builtin_amdgcn_mfma_f32_16x16x32_bf16(                \
                ones, af[qs][0], lacc[qs], 0, 0, 0);                           \
            lacc[qs] = __builtin_amdgcn_mfma_f32_16x16x32_bf16(                \
                ones, af[qs][1], lacc[qs], 0, 0, 0);                           \
        }                                                                      \
        __builtin_amdgcn_s_setprio(0);                                         \
    } while (0)

    bf16x8 kfA[2][4], kfB[2][4], vf[2][4];

    // prologue: K(0) in flight early
    LOAD_KF(kfA, 0);

    for (int kb = 0; kb < Ssz; kb += 128) {
        // tile kb: uses kfA; prefetch K(kb+64) into kfB after QK
        LOAD_VF(vf, kb);
        ATTN_TILE(kfA, vf,
                  if (kb + 64 < Ssz) LOAD_KF(kfB, kb + 64));
        // tile kb+64: uses kfB; prefetch K(kb+128) into kfA after QK
        LOAD_VF(vf, kb + 64);
        ATTN_TILE(kfB, vf,
                  if (kb + 128 < Ssz) LOAD_KF(kfA, kb + 128));
    }

    // epilogue: per-lane row-sum (col=q=l16), f32x4 stores along d
    #pragma unroll
    for (int qs = 0; qs < 2; ++qs) {
        const float linv = 1.f / (lacc[qs][0] + 1e-8f);
        const int q = qt * 128 + wave * 32 + qs * 16 + l16;
        float* obase = out + ((size_t)b * Ssz + q) * Dsz + h * DKsz;
        #pragma unroll
        for (int ns = 0; ns < 4; ++ns) {
            f32x4 o = oacc[qs][ns] * linv;
            *(f32x4*)(obase + ns * 16 + quad * 4) = o;
        }
    }
#undef ATTN_TILE
#undef LOAD_KF
#undef LOAD_VF
}

extern "C" void kernel_launch(void* const* d_in, const int* in_sizes, int n_in,
                              void* d_out, int out_size, void* d_ws, size_t ws_size,
                              hipStream_t stream) {
    const float* x  = (const float*)d_in[0];
    const float* Wq = (const float*)d_in[1];
    const float* Wk = (const float*)d_in[2];
    const float* Wv = (const float*)d_in[3];
    float* out = (float*)d_out;

    const size_t per = (size_t)Bsz * Hsz * Ssz * DKsz;  // 4,194,304 elems
    __bf16* Qw  = (__bf16*)d_ws;
    __bf16* Kw  = Qw + per;
    __bf16* VTw = Kw + per;
    __bf16* xb  = VTw + per;
    __bf16* Wb  = xb + per;                              // 786,432 elems

    cvt_kernel<<<4864, 256, 0, stream>>>(x, Wq, Wk, Wv, xb, Wb);
    qkv_kernel<<<768, 256, 0, stream>>>(xb, Wb, Qw, Kw, VTw);
    attn_kernel<<<dim3(Bsz * Hsz, Ssz / 128), 256, 0, stream>>>(Qw, Kw, VTw, out);
}

// Round 9
// 144.138 us; speedup vs baseline: 1.4501x; 1.4501x over previous
//
#include <hip/hip_runtime.h>
#include <hip/hip_bf16.h>

#define Bsz 4
#define Ssz 2048
#define Dsz 512
#define Hsz 8
#define DKsz 64

typedef __bf16 bf16x8 __attribute__((ext_vector_type(8)));
typedef __bf16 bf16x4 __attribute__((ext_vector_type(4)));
typedef float f32x4 __attribute__((ext_vector_type(4)));

// chunk-swizzled element offset: 16B chunk c of a 64-elem (128B) row, XOR row&7
#define SWE(c, row) ((((c) ^ ((row) & 7)) * 8))

// direct global->LDS 16B/lane copy (lane l writes lds_base + l*16)
#define GLL16(g, l) __builtin_amdgcn_global_load_lds(                      \
    (const __attribute__((address_space(1))) void*)(g),                    \
    (__attribute__((address_space(3))) void*)(l), 16, 0, 0)

__device__ inline bf16x8 cvt8(float4 a, float4 b) {
    bf16x8 r;
    r[0] = (__bf16)a.x; r[1] = (__bf16)a.y; r[2] = (__bf16)a.z; r[3] = (__bf16)a.w;
    r[4] = (__bf16)b.x; r[5] = (__bf16)b.y; r[6] = (__bf16)b.z; r[7] = (__bf16)b.w;
    return r;
}

// ---------------------------------------------------------------------------
// Fused qkv projection reading FP32 x/W DIRECTLY (cvt kernel eliminated:
// the fp32->bf16 conversion happens at prefetch time in registers — same
// VGPR count as the verified R0 bf16 skeleton, +64 v_cvt/thread/iter which
// qkv's ~60%-idle VALU absorbs). Removes one dispatch + launch gap + the
// xb/Wb HBM round-trip. L2-LOCALITY SWIZZLED grid (1-D, 768 blocks):
// XCD = lin&7; per XCD, 12 time-adjacent blocks share ONE x-tile and sweep
// all 12 (tn,which) W-tiles. 128x128 tile, swizzled LDS (reg-staged, both
// sides swizzled), reg prefetch, packed 8B stores.
// which<2 (Q/K): C = W-tile x x-tile -> rows=e (in-lane), cols=s.
// which==2 (V) : C = x-tile x W-tile -> rows=s (in-lane), cols=e -> V^T.
__global__ __launch_bounds__(256, 3) void qkv_kernel(
    const float* __restrict__ x, const float* __restrict__ Wq,
    const float* __restrict__ Wk, const float* __restrict__ Wv,
    __bf16* __restrict__ Qo, __bf16* __restrict__ Ko, __bf16* __restrict__ Vo)
{
    __shared__ __bf16 xs[128][64];
    __shared__ __bf16 wsh[128][64];

    const int tid  = threadIdx.x;
    const int lane = tid & 63;
    const int wave = tid >> 6;
    const int quad = lane >> 4;
    const int l16  = lane & 15;
    const int wm   = (wave & 1) * 64;
    const int wn   = (wave >> 1) * 64;

    const int lin = blockIdx.x;
    const int xcd = lin & 7;
    const int idx = lin >> 3;             // 0..95
    const int tnw = idx % 12;             // fast per XCD: sweeps (tn, which)
    const int tmh = idx / 12;             // slow: x-tile group
    const int tm  = (tmh * 8 + xcd) * 128;
    const int tn  = (tnw & 3) * 128;
    const int which = tnw >> 2;           // 0=Q 1=K 2=V
    const bool VM = (which == 2);
    const float* W = (which == 0) ? Wq : (which == 1) ? Wk : Wv;

    const int srow = tid >> 3;            // 0..31 (+32i covers 128 rows)
    const int sc   = tid & 7;             // 16B(bf16)/32B(fp32) chunk of row
    const int swz  = SWE(sc, srow);       // (srow+32i)&7 == srow&7: i-invariant

    const float* xg = x + (size_t)(tm + srow) * Dsz + sc * 8;
    const float* wg = W + (size_t)(tn + srow) * Dsz + sc * 8;

    bf16x8 px[4], pw[4];
    #pragma unroll
    for (int i = 0; i < 4; ++i) {
        px[i] = cvt8(*(const float4*)(xg + (size_t)(32 * i) * Dsz),
                     *(const float4*)(xg + (size_t)(32 * i) * Dsz + 4));
        pw[i] = cvt8(*(const float4*)(wg + (size_t)(32 * i) * Dsz),
                     *(const float4*)(wg + (size_t)(32 * i) * Dsz + 4));
    }

    f32x4 acc[4][4];
    #pragma unroll
    for (int i = 0; i < 4; ++i)
        #pragma unroll
        for (int j = 0; j < 4; ++j) acc[i][j] = (f32x4){0.f, 0.f, 0.f, 0.f};

    const __bf16 (*Ash)[64] = VM ? xs : wsh;
    const __bf16 (*Bsh)[64] = VM ? wsh : xs;

    for (int k0 = 0; k0 < Dsz; k0 += 64) {
        __syncthreads();
        #pragma unroll
        for (int i = 0; i < 4; ++i) {
            *(bf16x8*)&xs[srow + 32 * i][swz]  = px[i];
            *(bf16x8*)&wsh[srow + 32 * i][swz] = pw[i];
        }
        __syncthreads();
        if (k0 + 64 < Dsz) {
            #pragma unroll
            for (int i = 0; i < 4; ++i) {
                px[i] = cvt8(*(const float4*)(xg + (size_t)(32 * i) * Dsz + k0 + 64),
                             *(const float4*)(xg + (size_t)(32 * i) * Dsz + k0 + 68));
                pw[i] = cvt8(*(const float4*)(wg + (size_t)(32 * i) * Dsz + k0 + 64),
                             *(const float4*)(wg + (size_t)(32 * i) * Dsz + k0 + 68));
            }
        }

        #pragma unroll
        for (int kk = 0; kk < 2; ++kk) {
            bf16x8 fa[4], fb[4];
            #pragma unroll
            for (int mi = 0; mi < 4; ++mi) {
                const int row = wm + mi * 16 + l16;
                fa[mi] = *(const bf16x8*)&Ash[row][SWE(kk * 4 + quad, row)];
            }
            #pragma unroll
            for (int ni = 0; ni < 4; ++ni) {
                const int row = wn + ni * 16 + l16;
                fb[ni] = *(const bf16x8*)&Bsh[row][SWE(kk * 4 + quad, row)];
            }
            #pragma unroll
            for (int mi = 0; mi < 4; ++mi)
                #pragma unroll
                for (int ni = 0; ni < 4; ++ni)
                    acc[mi][ni] = __builtin_amdgcn_mfma_f32_16x16x32_bf16(
                        fa[mi], fb[ni], acc[mi][ni], 0, 0, 0);
        }
    }

    if (!VM) {
        const float scale = (which == 0) ? 0.125f * 1.44269504088896340736f : 1.0f;
        __bf16* dst = (which == 0) ? Qo : Ko;
        // rows = e (W-dim), in-lane regs r span 4 consecutive e -> 4 consecutive d
        #pragma unroll
        for (int mi = 0; mi < 4; ++mi) {
            const int e0 = tn + wm + mi * 16 + quad * 4;
            const int h = e0 >> 6, d0 = e0 & 63;
            #pragma unroll
            for (int ni = 0; ni < 4; ++ni) {
                const int sf = tm + wn + ni * 16 + l16;
                const int b = sf >> 11, s = sf & (Ssz - 1);
                bf16x4 p;
                #pragma unroll
                for (int r = 0; r < 4; ++r) p[r] = (__bf16)(acc[mi][ni][r] * scale);
                *(bf16x4*)&dst[((((size_t)(b * Hsz + h) * Ssz + s)) << 6) + d0] = p;
            }
        }
    } else {
        // rows = s, in-lane regs r span 4 consecutive s -> V^T packed stores
        #pragma unroll
        for (int mi = 0; mi < 4; ++mi) {
            const int sf0 = tm + wm + mi * 16 + quad * 4;
            const int b = sf0 >> 11, s0 = sf0 & (Ssz - 1);
            #pragma unroll
            for (int ni = 0; ni < 4; ++ni) {
                const int e = tn + wn + ni * 16 + l16;
                const int h = e >> 6, d = e & 63;
                bf16x4 p;
                #pragma unroll
                for (int r = 0; r < 4; ++r) p[r] = (__bf16)acc[mi][ni][r];
                *(bf16x4*)&Vo[(((size_t)(b * Hsz + h) * DKsz + d) << 11) + s0] = p;
            }
        }
    }
}

// ---------------------------------------------------------------------------
// Flash attention — EXACT R4-BEST STRUCTURE (measured 48.7 us; R8's
// no-staging variant was 126.8 us: LDS staging is the latency decoupler,
// gload_lds bulk DMA >> 32 per-wave latency-exposed L2 loads).
//  (1) ks/vs double-buffered, ONE barrier per tile (stage overlaps compute).
//  (2) K/V staged via global_load_lds w=16 (linear LDS dest + pre-XORed
//      global source chunk, rule #21).
//  (3) ps split psA/psB per qs + phase-batched compute (16-MFMA QK cluster
//      -> pack both -> 20-MFMA PV cluster).
// S computed transposed (A=K,B=Q) -> P^T packs to b64 LDS writes; PV swapped
// (A=V^T, B=P^T) -> O^T regs -> f32x4 stores; row-sums via ones-MFMA.
__global__ __launch_bounds__(256, 2) void attn_kernel(
    const __bf16* __restrict__ Q, const __bf16* __restrict__ K,
    const __bf16* __restrict__ VT, float* __restrict__ out)
{
    __shared__ __bf16 ks[2][64][64];     // K[s_local][dk], swizzled chunks
    __shared__ __bf16 vs[2][64][64];     // V^T[dk][s_local], swizzled chunks
    __shared__ __bf16 psA[4][16][64];    // per-wave P^T buffer, qs=0
    __shared__ __bf16 psB[4][16][64];    // per-wave P^T buffer, qs=1

    const int tid  = threadIdx.x;
    const int lane = tid & 63;
    const int wave = tid >> 6;
    const int quad = lane >> 4;
    const int l16  = lane & 15;

    const int bh = blockIdx.x;           // all q-blocks of a bh share an XCD L2
    const int qt = blockIdx.y;           // 128-row q tile
    const int b  = bh >> 3;
    const int h  = bh & 7;

    const __bf16* Qb = Q  + (size_t)bh * Ssz * DKsz;
    const __bf16* Kb = K  + (size_t)bh * Ssz * DKsz;
    const __bf16* Vb = VT + (size_t)bh * DKsz * Ssz;

    // Q fragments: lane l16 = q-local row, quad*8 = dk chunk
    bf16x8 qf[2][2];
    #pragma unroll
    for (int qs = 0; qs < 2; ++qs) {
        const __bf16* qrow = Qb + (size_t)(qt * 128 + wave * 32 + qs * 16 + l16) * DKsz;
        qf[qs][0] = *(const bf16x8*)(qrow + quad * 8);
        qf[qs][1] = *(const bf16x8*)(qrow + 32 + quad * 8);
    }

    bf16x8 ones;
    #pragma unroll
    for (int i = 0; i < 8; ++i) ones[i] = (__bf16)1.0f;

    f32x4 oacc[2][4];
    #pragma unroll
    for (int qs = 0; qs < 2; ++qs)
        #pragma unroll
        for (int i = 0; i < 4; ++i) oacc[qs][i] = (f32x4){0.f, 0.f, 0.f, 0.f};
    f32x4 lacc[2] = {(f32x4){0.f, 0.f, 0.f, 0.f}, (f32x4){0.f, 0.f, 0.f, 0.f}};

    // gload_lds staging geometry: per wave, issue covers 8 rows (1 KB);
    // lane l -> row wave*8+(l>>3), LINEAR chunk l&7; source chunk pre-XORed
    // with (row&7)=(l>>3) so swizzled read side sees the expected layout.
    const int rl  = lane >> 3;
    const int gch = (lane & 7) ^ rl;     // pre-swizzled 16B chunk

#define STAGE_KV(DST, KBASE)                                                   \
    do {                                                                       \
        const __bf16* kgs = Kb + (size_t)((KBASE) + wave * 8 + rl) * DKsz      \
                               + gch * 8;                                      \
        const __bf16* vgs = Vb + (size_t)(wave * 8 + rl) * Ssz + (KBASE)       \
                               + gch * 8;                                      \
        GLL16(kgs,                        &ks[DST][wave * 8][0]);              \
        GLL16(kgs + (size_t)32 * DKsz,    &ks[DST][wave * 8 + 32][0]);         \
        GLL16(vgs,                        &vs[DST][wave * 8][0]);              \
        GLL16(vgs + (size_t)32 * Ssz,     &vs[DST][wave * 8 + 32][0]);         \
    } while (0)

    // prologue: stage tile 0 into buf 0; drain; barrier
    STAGE_KV(0, 0);
    asm volatile("s_waitcnt vmcnt(0)\n\ts_barrier" ::: "memory");

#define ATTN_TILE(CUR, KB)                                                     \
    do {                                                                       \
        if ((KB) + 64 < Ssz) STAGE_KV((CUR) ^ 1, (KB) + 64);                   \
        bf16x8 kf[2][4], vf[2][4];                                             \
        _Pragma("unroll")                                                      \
        for (int kk = 0; kk < 2; ++kk)                                         \
            _Pragma("unroll")                                                  \
            for (int ns = 0; ns < 4; ++ns) {                                   \
                const int row = ns * 16 + l16;                                 \
                kf[kk][ns] = *(const bf16x8*)&ks[CUR][row][SWE(kk*4+quad,row)];\
                vf[kk][ns] = *(const bf16x8*)&vs[CUR][row][SWE(kk*4+quad,row)];\
            }                                                                  \
        __builtin_amdgcn_s_setprio(1);                                         \
        f32x4 st[2][4];                                                        \
        _Pragma("unroll")                                                      \
        for (int qs = 0; qs < 2; ++qs)                                         \
            _Pragma("unroll")                                                  \
            for (int ns = 0; ns < 4; ++ns) {                                   \
                f32x4 t = (f32x4){0.f, 0.f, 0.f, 0.f};                         \
                t = __builtin_amdgcn_mfma_f32_16x16x32_bf16(                   \
                        kf[0][ns], qf[qs][0], t, 0, 0, 0);                     \
                t = __builtin_amdgcn_mfma_f32_16x16x32_bf16(                   \
                        kf[1][ns], qf[qs][1], t, 0, 0, 0);                     \
                st[qs][ns] = t;                                                \
            }                                                                  \
        __builtin_amdgcn_s_setprio(0);                                         \
        _Pragma("unroll")                                                      \
        for (int qs = 0; qs < 2; ++qs)                                         \
            _Pragma("unroll")                                                  \
            for (int ns = 0; ns < 4; ++ns) {                                   \
                bf16x4 pp;                                                     \
                _Pragma("unroll")                                              \
                for (int r = 0; r < 4; ++r)                                    \
                    pp[r] = (__bf16)__builtin_amdgcn_exp2f(st[qs][ns][r]);     \
                __bf16* pbase = qs ? &psB[wave][l16][0] : &psA[wave][l16][0];  \
                const int c = ns * 2 + (quad >> 1);                            \
                *(bf16x4*)&pbase[((c ^ (l16 & 7)) << 3) + ((quad & 1) << 2)]   \
                    = pp;                                                      \
            }                                                                  \
        bf16x8 af[2][2];                                                       \
        af[0][0] = *(const bf16x8*)&psA[wave][l16][SWE(quad, l16)];            \
        af[0][1] = *(const bf16x8*)&psA[wave][l16][SWE(4 + quad, l16)];        \
        af[1][0] = *(const bf16x8*)&psB[wave][l16][SWE(quad, l16)];            \
        af[1][1] = *(const bf16x8*)&psB[wave][l16][SWE(4 + quad, l16)];        \
        __builtin_amdgcn_s_setprio(1);                                         \
        _Pragma("unroll")                                                      \
        for (int qs = 0; qs < 2; ++qs) {                                       \
            _Pragma("unroll")                                                  \
            for (int ns = 0; ns < 4; ++ns) {                                   \
                oacc[qs][ns] = __builtin_amdgcn_mfma_f32_16x16x32_bf16(        \
                    vf[0][ns], af[qs][0], oacc[qs][ns], 0, 0, 0);              \
                oacc[qs][ns] = __builtin_amdgcn_mfma_f32_16x16x32_bf16(        \
                    vf[1][ns], af[qs][1], oacc[qs][ns], 0, 0, 0);              \
            }                                                                  \
            lacc[qs] = __builtin_amdgcn_mfma_f32_16x16x32_bf16(                \
                ones, af[qs][0], lacc[qs], 0, 0, 0);                           \
            lacc[qs] = __builtin_amdgcn_mfma_f32_16x16x32_bf16(                \
                ones, af[qs][1], lacc[qs], 0, 0, 0);                           \
        }                                                                      \
        __builtin_amdgcn_s_setprio(0);                                         \
        asm volatile("s_waitcnt vmcnt(0) lgkmcnt(0)\n\ts_barrier"              \
                     ::: "memory");                                           \
    } while (0)

    for (int kb = 0; kb < Ssz; kb += 128) {
        ATTN_TILE(0, kb);
        ATTN_TILE(1, kb + 64);
    }

    // epilogue: per-lane row-sum (col=q=l16), f32x4 stores along d
    #pragma unroll
    for (int qs = 0; qs < 2; ++qs) {
        const float linv = 1.f / (lacc[qs][0] + 1e-8f);
        const int q = qt * 128 + wave * 32 + qs * 16 + l16;
        float* obase = out + ((size_t)b * Ssz + q) * Dsz + h * DKsz;
        #pragma unroll
        for (int ns = 0; ns < 4; ++ns) {
            f32x4 o = oacc[qs][ns] * linv;
            *(f32x4*)(obase + ns * 16 + quad * 4) = o;
        }
    }
#undef ATTN_TILE
#undef STAGE_KV
}

extern "C" void kernel_launch(void* const* d_in, const int* in_sizes, int n_in,
                              void* d_out, int out_size, void* d_ws, size_t ws_size,
                              hipStream_t stream) {
    const float* x  = (const float*)d_in[0];
    const float* Wq = (const float*)d_in[1];
    const float* Wk = (const float*)d_in[2];
    const float* Wv = (const float*)d_in[3];
    float* out = (float*)d_out;

    const size_t per = (size_t)Bsz * Hsz * Ssz * DKsz;  // 4,194,304 elems
    __bf16* Qw  = (__bf16*)d_ws;
    __bf16* Kw  = Qw + per;
    __bf16* VTw = Kw + per;

    qkv_kernel<<<768, 256, 0, stream>>>(x, Wq, Wk, Wv, Qw, Kw, VTw);
    attn_kernel<<<dim3(Bsz * Hsz, Ssz / 128), 256, 0, stream>>>(Qw, Kw, VTw, out);
}

// Round 11
// 134.609 us; speedup vs baseline: 1.5528x; 1.0708x over previous
//
#include <hip/hip_runtime.h>
#include <hip/hip_bf16.h>

#define Bsz 4
#define Ssz 2048
#define Dsz 512
#define Hsz 8
#define DKsz 64

typedef __bf16 bf16x8 __attribute__((ext_vector_type(8)));
typedef __bf16 bf16x4 __attribute__((ext_vector_type(4)));
typedef float f32x4 __attribute__((ext_vector_type(4)));

// chunk-swizzled element offset: 16B chunk c of a 64-elem (128B) row, XOR row&7
#define SWE(c, row) ((((c) ^ ((row) & 7)) * 8))

// direct global->LDS 16B/lane copy (lane l writes lds_base + l*16)
#define GLL16(g, l) __builtin_amdgcn_global_load_lds(                      \
    (const __attribute__((address_space(1))) void*)(g),                    \
    (__attribute__((address_space(3))) void*)(l), 16, 0, 0)

// ---------------------------------------------------------------------------
// cvt: x (4.19M fp32) + Wq|Wk|Wv (3 x 262144 fp32) -> bf16 in ws.
// (R9 showed fusing this into qkv regresses: fp32 staging doubles qkv's
// L2/HBM bytes and XCD footprint. Separate cvt + bf16 qkv measured best.)
__global__ __launch_bounds__(256) void cvt_kernel(
    const float* __restrict__ x, const float* __restrict__ Wq,
    const float* __restrict__ Wk, const float* __restrict__ Wv,
    __bf16* __restrict__ xb, __bf16* __restrict__ Wb)
{
    const int i = blockIdx.x * 256 + threadIdx.x;   // float4 index
    const int XN4 = (Bsz * Ssz * Dsz) / 4;          // 1,048,576
    const float* src;
    __bf16* dst;
    int off;
    if (i < XN4) {
        src = x; dst = xb; off = i;
    } else {
        int j = i - XN4;                             // 0 .. 196607
        int w = j >> 16;                             // 0,1,2
        off = j & 65535;
        src = (w == 0) ? Wq : (w == 1) ? Wk : Wv;
        dst = Wb + (size_t)w * (Dsz * Dsz);
    }
    float4 v = ((const float4*)src)[off];
    __bf16 o[4] = {(__bf16)v.x, (__bf16)v.y, (__bf16)v.z, (__bf16)v.w};
    *(uint2*)(dst + (size_t)off * 4) = *(uint2*)o;
}

// ---------------------------------------------------------------------------
// Fused qkv projection, L2-LOCALITY SWIZZLED grid (1-D, 768 blocks).
// Staging via global_load_lds width=16: LDS dest LINEAR (lane l -> base+16l,
// 8 rows/wave), global source chunk PRE-SWIZZLED with the read-side XOR
// involution (chunk ^= row&7) -> rule #21 satisfied, coalescing preserved.
// 128x128 tile, 2-barrier K-loop, which<2 (Q/K): C = W-tile x x-tile;
// which==2 (V): C = x-tile x W-tile -> V^T.   [verified R3-R7: passed]
__global__ __launch_bounds__(256, 3) void qkv_kernel(
    const __bf16* __restrict__ xb, const __bf16* __restrict__ Wb,
    __bf16* __restrict__ Qo, __bf16* __restrict__ Ko, __bf16* __restrict__ Vo)
{
    __shared__ __bf16 xs[128][64];
    __shared__ __bf16 wsh[128][64];

    const int tid  = threadIdx.x;
    const int lane = tid & 63;
    const int wave = tid >> 6;
    const int quad = lane >> 4;
    const int l16  = lane & 15;
    const int wm   = (wave & 1) * 64;
    const int wn   = (wave >> 1) * 64;

    const int lin = blockIdx.x;
    const int xcd = lin & 7;
    const int idx = lin >> 3;             // 0..95
    const int tnw = idx % 12;             // fast per XCD: sweeps (tn, which)
    const int tmh = idx / 12;             // slow: x-tile group
    const int tm  = (tmh * 8 + xcd) * 128;
    const int tn  = (tnw & 3) * 128;
    const int which = tnw >> 2;           // 0=Q 1=K 2=V
    const bool VM = (which == 2);
    const __bf16* W = Wb + (size_t)which * (Dsz * Dsz);

    // direct-to-LDS staging: wave covers rows [wave*8, wave*8+8) per issue,
    // lane l -> row wave*8+(l>>3), linear chunk l&7; source chunk pre-XORed.
    const int rl  = lane >> 3;            // 0..7
    const int gch = (lane & 7) ^ rl;      // pre-swizzled 16B chunk
    const __bf16* xsrc = xb + (size_t)(tm + wave * 8 + rl) * Dsz + gch * 8;
    const __bf16* wsrc = W  + (size_t)(tn + wave * 8 + rl) * Dsz + gch * 8;

    f32x4 acc[4][4];
    #pragma unroll
    for (int i = 0; i < 4; ++i)
        #pragma unroll
        for (int j = 0; j < 4; ++j) acc[i][j] = (f32x4){0.f, 0.f, 0.f, 0.f};

    const __bf16 (*Ash)[64] = VM ? xs : wsh;
    const __bf16 (*Bsh)[64] = VM ? wsh : xs;

    for (int k0 = 0; k0 < Dsz; k0 += 64) {
        __syncthreads();                  // previous tile fully consumed
        #pragma unroll
        for (int i = 0; i < 4; ++i) {
            GLL16(xsrc + (size_t)(32 * i) * Dsz + k0, &xs[wave * 8 + 32 * i][0]);
            GLL16(wsrc + (size_t)(32 * i) * Dsz + k0, &wsh[wave * 8 + 32 * i][0]);
        }
        asm volatile("s_waitcnt vmcnt(0)" ::: "memory");
        __syncthreads();

        #pragma unroll
        for (int kk = 0; kk < 2; ++kk) {
            bf16x8 fa[4], fb[4];
            #pragma unroll
            for (int mi = 0; mi < 4; ++mi) {
                const int row = wm + mi * 16 + l16;
                fa[mi] = *(const bf16x8*)&Ash[row][SWE(kk * 4 + quad, row)];
            }
            #pragma unroll
            for (int ni = 0; ni < 4; ++ni) {
                const int row = wn + ni * 16 + l16;
                fb[ni] = *(const bf16x8*)&Bsh[row][SWE(kk * 4 + quad, row)];
            }
            #pragma unroll
            for (int mi = 0; mi < 4; ++mi)
                #pragma unroll
                for (int ni = 0; ni < 4; ++ni)
                    acc[mi][ni] = __builtin_amdgcn_mfma_f32_16x16x32_bf16(
                        fa[mi], fb[ni], acc[mi][ni], 0, 0, 0);
        }
    }

    if (!VM) {
        const float scale = (which == 0) ? 0.125f * 1.44269504088896340736f : 1.0f;
        __bf16* dst = (which == 0) ? Qo : Ko;
        // rows = e (W-dim), in-lane regs r span 4 consecutive e -> 4 consecutive d
        #pragma unroll
        for (int mi = 0; mi < 4; ++mi) {
            const int e0 = tn + wm + mi * 16 + quad * 4;
            const int h = e0 >> 6, d0 = e0 & 63;
            #pragma unroll
            for (int ni = 0; ni < 4; ++ni) {
                const int sf = tm + wn + ni * 16 + l16;
                const int b = sf >> 11, s = sf & (Ssz - 1);
                bf16x4 p;
                #pragma unroll
                for (int r = 0; r < 4; ++r) p[r] = (__bf16)(acc[mi][ni][r] * scale);
                *(bf16x4*)&dst[((((size_t)(b * Hsz + h) * Ssz + s)) << 6) + d0] = p;
            }
        }
    } else {
        // rows = s, in-lane regs r span 4 consecutive s -> V^T packed stores
        #pragma unroll
        for (int mi = 0; mi < 4; ++mi) {
            const int sf0 = tm + wm + mi * 16 + quad * 4;
            const int b = sf0 >> 11, s0 = sf0 & (Ssz - 1);
            #pragma unroll
            for (int ni = 0; ni < 4; ++ni) {
                const int e = tn + wn + ni * 16 + l16;
                const int h = e >> 6, d = e & 63;
                bf16x4 p;
                #pragma unroll
                for (int r = 0; r < 4; ++r) p[r] = (__bf16)acc[mi][ni][r];
                *(bf16x4*)&Vo[(((size_t)(b * Hsz + h) * DKsz + d) << 11) + s0] = p;
            }
        }
    }
}

// ---------------------------------------------------------------------------
// Flash attention = R4-best structure + T4 COUNTED-VMCNT TRIPLE-BUFFER.
// R4/R5 always drained vmcnt(0) at the tile barrier, waiting on the stage
// issued THIS tile (~600 cyc cover — HBM misses at ~900 cyc stall the block).
// Now: ks/vs x3 buffers; tile T issues stage(T+2); trailing wait is
// vmcnt(4) = "stage(T+1) landed" (issued a FULL tile ago, ~1200+ cyc cover)
// while stage(T+2)'s 4 loads stay in flight ACROSS the barrier (T4, the
// 8-phase GEMM's +38-73% lever). Counting is sound: the compute phase has
// zero other VMEM per wave (Q drained in prologue vmcnt(0)), so
// outstanding == own 4 stage loads per tile, FIFO-ordered.
// LDS 64 KB x 2 blocks/CU = 128 KB <= 160. Buffer rotation is runtime-
// indexed (LDS addressing, not registers — rule #20 unaffected).
// Note: SQ_LDS_BANK_CONFLICT 2^21 = 4/b64-write = inherent 512B width cost
// (bank-balanced by audit) — not actionable.
// S computed transposed (A=K,B=Q) -> P^T packs to b64 LDS writes; PV swapped
// (A=V^T, B=P^T) -> O^T regs -> f32x4 stores; row-sums via ones-MFMA.
__global__ __launch_bounds__(256, 2) void attn_kernel(
    const __bf16* __restrict__ Q, const __bf16* __restrict__ K,
    const __bf16* __restrict__ VT, float* __restrict__ out)
{
    __shared__ __bf16 ks[3][64][64];     // K[s_local][dk], swizzled chunks
    __shared__ __bf16 vs[3][64][64];     // V^T[dk][s_local], swizzled chunks
    __shared__ __bf16 psA[4][16][64];    // per-wave P^T buffer, qs=0
    __shared__ __bf16 psB[4][16][64];    // per-wave P^T buffer, qs=1

    const int tid  = threadIdx.x;
    const int lane = tid & 63;
    const int wave = tid >> 6;
    const int quad = lane >> 4;
    const int l16  = lane & 15;

    const int bh = blockIdx.x;           // all q-blocks of a bh share an XCD L2
    const int qt = blockIdx.y;           // 128-row q tile
    const int b  = bh >> 3;
    const int h  = bh & 7;

    const __bf16* Qb = Q  + (size_t)bh * Ssz * DKsz;
    const __bf16* Kb = K  + (size_t)bh * Ssz * DKsz;
    const __bf16* Vb = VT + (size_t)bh * DKsz * Ssz;

    // Q fragments: lane l16 = q-local row, quad*8 = dk chunk
    bf16x8 qf[2][2];
    #pragma unroll
    for (int qs = 0; qs < 2; ++qs) {
        const __bf16* qrow = Qb + (size_t)(qt * 128 + wave * 32 + qs * 16 + l16) * DKsz;
        qf[qs][0] = *(const bf16x8*)(qrow + quad * 8);
        qf[qs][1] = *(const bf16x8*)(qrow + 32 + quad * 8);
    }

    bf16x8 ones;
    #pragma unroll
    for (int i = 0; i < 8; ++i) ones[i] = (__bf16)1.0f;

    f32x4 oacc[2][4];
    #pragma unroll
    for (int qs = 0; qs < 2; ++qs)
        #pragma unroll
        for (int i = 0; i < 4; ++i) oacc[qs][i] = (f32x4){0.f, 0.f, 0.f, 0.f};
    f32x4 lacc[2] = {(f32x4){0.f, 0.f, 0.f, 0.f}, (f32x4){0.f, 0.f, 0.f, 0.f}};

    // gload_lds staging geometry: per wave, issue covers 8 rows (1 KB);
    // lane l -> row wave*8+(l>>3), LINEAR chunk l&7; source chunk pre-XORed
    // with (row&7)=(l>>3) so swizzled read side sees the expected layout.
    const int rl  = lane >> 3;
    const int gch = (lane & 7) ^ rl;     // pre-swizzled 16B chunk

#define STAGE_KV(DST, KBASE)                                                   \
    do {                                                                       \
        const __bf16* kgs = Kb + (size_t)((KBASE) + wave * 8 + rl) * DKsz      \
                               + gch * 8;                                      \
        const __bf16* vgs = Vb + (size_t)(wave * 8 + rl) * Ssz + (KBASE)       \
                               + gch * 8;                                      \
        GLL16(kgs,                        &ks[DST][wave * 8][0]);              \
        GLL16(kgs + (size_t)32 * DKsz,    &ks[DST][wave * 8 + 32][0]);         \
        GLL16(vgs,                        &vs[DST][wave * 8][0]);              \
        GLL16(vgs + (size_t)32 * Ssz,     &vs[DST][wave * 8 + 32][0]);         \
    } while (0)

// tile compute on buffer CUR (runtime index): kf/vf bulk read -> batched QK
// (16 MFMA) -> exp2+pack both qs -> batched PV+lacc (20 MFMA). No sync.
#define ATTN_COMPUTE(CUR)                                                      \
    do {                                                                       \
        bf16x8 kf[2][4], vf[2][4];                                             \
        _Pragma("unroll")                                                      \
        for (int kk = 0; kk < 2; ++kk)                                         \
            _Pragma("unroll")                                                  \
            for (int ns = 0; ns < 4; ++ns) {                                   \
                const int row = ns * 16 + l16;                                 \
                kf[kk][ns] = *(const bf16x8*)&ks[CUR][row][SWE(kk*4+quad,row)];\
                vf[kk][ns] = *(const bf16x8*)&vs[CUR][row][SWE(kk*4+quad,row)];\
            }                                                                  \
        __builtin_amdgcn_s_setprio(1);                                         \
        f32x4 st[2][4];                                                        \
        _Pragma("unroll")                                                      \
        for (int qs = 0; qs < 2; ++qs)                                         \
            _Pragma("unroll")                                                  \
            for (int ns = 0; ns < 4; ++ns) {                                   \
                f32x4 t = (f32x4){0.f, 0.f, 0.f, 0.f};                         \
                t = __builtin_amdgcn_mfma_f32_16x16x32_bf16(                   \
                        kf[0][ns], qf[qs][0], t, 0, 0, 0);                     \
                t = __builtin_amdgcn_mfma_f32_16x16x32_bf16(                   \
                        kf[1][ns], qf[qs][1], t, 0, 0, 0);                     \
                st[qs][ns] = t;                                                \
            }                                                                  \
        __builtin_amdgcn_s_setprio(0);                                         \
        _Pragma("unroll")                                                      \
        for (int qs = 0; qs < 2; ++qs)                                         \
            _Pragma("unroll")                                                  \
            for (int ns = 0; ns < 4; ++ns) {                                   \
                bf16x4 pp;                                                     \
                _Pragma("unroll")                                              \
                for (int r = 0; r < 4; ++r)                                    \
                    pp[r] = (__bf16)__builtin_amdgcn_exp2f(st[qs][ns][r]);     \
                __bf16* pbase = qs ? &psB[wave][l16][0] : &psA[wave][l16][0];  \
                const int c = ns * 2 + (quad >> 1);                            \
                *(bf16x4*)&pbase[((c ^ (l16 & 7)) << 3) + ((quad & 1) << 2)]   \
                    = pp;                                                      \
            }                                                                  \
        bf16x8 af[2][2];                                                       \
        af[0][0] = *(const bf16x8*)&psA[wave][l16][SWE(quad, l16)];            \
        af[0][1] = *(const bf16x8*)&psA[wave][l16][SWE(4 + quad, l16)];        \
        af[1][0] = *(const bf16x8*)&psB[wave][l16][SWE(quad, l16)];            \
        af[1][1] = *(const bf16x8*)&psB[wave][l16][SWE(4 + quad, l16)];        \
        __builtin_amdgcn_s_setprio(1);                                         \
        _Pragma("unroll")                                                      \
        for (int qs = 0; qs < 2; ++qs) {                                       \
            _Pragma("unroll")                                                  \
            for (int ns = 0; ns < 4; ++ns) {                                   \
                oacc[qs][ns] = __builtin_amdgcn_mfma_f32_16x16x32_bf16(        \
                    vf[0][ns], af[qs][0], oacc[qs][ns], 0, 0, 0);              \
                oacc[qs][ns] = __builtin_amdgcn_mfma_f32_16x16x32_bf16(        \
                    vf[1][ns], af[qs][1], oacc[qs][ns], 0, 0, 0);              \
            }                                                                  \
            lacc[qs] = __builtin_amdgcn_mfma_f32_16x16x32_bf16(                \
                ones, af[qs][0], lacc[qs], 0, 0, 0);                           \
            lacc[qs] = __builtin_amdgcn_mfma_f32_16x16x32_bf16(                \
                ones, af[qs][1], lacc[qs], 0, 0, 0);                           \
        }                                                                      \
        __builtin_amdgcn_s_setprio(0);                                         \
    } while (0)

    // prologue: stage tiles 0,1; drain ALL vmem (incl. Q loads -> in-loop
    // vmcnt counting starts from a clean 0); publish.
    STAGE_KV(0, 0);
    STAGE_KV(1, 64);
    asm volatile("s_waitcnt vmcnt(0)\n\ts_barrier" ::: "memory");

    // main loop: tiles 0..29. Tile T: issue stage(T+2) -> outstanding 8;
    // compute(T); trailing vmcnt(4) waits stage(T+1) only (FIFO), leaving
    // stage(T+2) in flight across the barrier.
    int cur = 0;
    for (int t = 0; t < 30; ++t) {
        const int nx2 = (cur == 0) ? 2 : cur - 1;   // (t+2)%3
        STAGE_KV(nx2, t * 64 + 128);
        ATTN_COMPUTE(cur);
        asm volatile("s_waitcnt vmcnt(4) lgkmcnt(0)\n\ts_barrier" ::: "memory");
        cur = (cur == 2) ? 0 : cur + 1;
    }
    // tile 30: nothing left to stage; drain stage(31) fully before barrier.
    ATTN_COMPUTE(cur);
    asm volatile("s_waitcnt vmcnt(0) lgkmcnt(0)\n\ts_barrier" ::: "memory");
    cur = (cur == 2) ? 0 : cur + 1;
    // tile 31: last tile, no trailing sync needed before epilogue.
    ATTN_COMPUTE(cur);

    // epilogue: per-lane row-sum (col=q=l16), f32x4 stores along d
    #pragma unroll
    for (int qs = 0; qs < 2; ++qs) {
        const float linv = 1.f / (lacc[qs][0] + 1e-8f);
        const int q = qt * 128 + wave * 32 + qs * 16 + l16;
        float* obase = out + ((size_t)b * Ssz + q) * Dsz + h * DKsz;
        #pragma unroll
        for (int ns = 0; ns < 4; ++ns) {
            f32x4 o = oacc[qs][ns] * linv;
            *(f32x4*)(obase + ns * 16 + quad * 4) = o;
        }
    }
#undef ATTN_COMPUTE
#undef STAGE_KV
}

extern "C" void kernel_launch(void* const* d_in, const int* in_sizes, int n_in,
                              void* d_out, int out_size, void* d_ws, size_t ws_size,
                              hipStream_t stream) {
    const float* x  = (const float*)d_in[0];
    const float* Wq = (const float*)d_in[1];
    const float* Wk = (const float*)d_in[2];
    const float* Wv = (const float*)d_in[3];
    float* out = (float*)d_out;

    const size_t per = (size_t)Bsz * Hsz * Ssz * DKsz;  // 4,194,304 elems
    __bf16* Qw  = (__bf16*)d_ws;
    __bf16* Kw  = Qw + per;
    __bf16* VTw = Kw + per;
    __bf16* xb  = VTw + per;
    __bf16* Wb  = xb + per;                              // 786,432 elems

    cvt_kernel<<<4864, 256, 0, stream>>>(x, Wq, Wk, Wv, xb, Wb);
    qkv_kernel<<<768, 256, 0, stream>>>(xb, Wb, Qw, Kw, VTw);
    attn_kernel<<<dim3(Bsz * Hsz, Ssz / 128), 256, 0, stream>>>(Qw, Kw, VTw, out);
}